// Round 4
// baseline (13902.733 us; speedup 1.0000x reference)
//
#include <hip/hip_runtime.h>
#include <stdint.h>

// LPDNet forward on gfx950.
// Layout decisions:
//   h     : (B,N,64) fp32 rows  -> coalesced gather + fp32-exact knn distances
//   featb : (B,N,512) bf16 rows -> [x1 | x2 | x3], rows feed conv3 GEMM and x2 gather
//   idx1/idx2 : (B,N,20) int32
// bf16 everywhere in the conv path (fp32 accum); tolerance is 2% of max|ref|.

#define NB 8
#define NP 4096
#define NPTS (NB*NP)

typedef float  floatx4 __attribute__((ext_vector_type(4)));
typedef short  short8  __attribute__((ext_vector_type(8)));

__device__ __forceinline__ unsigned short f2bf(float f) {
  union { float f; uint32_t u; } v; v.f = f;
  uint32_t r = v.u + 0x7fffu + ((v.u >> 16) & 1u);   // RNE
  return (unsigned short)(r >> 16);
}
__device__ __forceinline__ float bf2f(unsigned short h) {
  union { uint32_t u; float f; } v; v.u = ((uint32_t)h) << 16;
  return v.f;
}

__device__ __forceinline__ floatx4 mfma_bf16(short8 a, short8 b, floatx4 c) {
  return __builtin_amdgcn_mfma_f32_16x16x32_bf16(a, b, c, 0, 0, 0);
}

// ---------------- K0: fp32 -> bf16 weight conversion (runs every launch) ----
__global__ void cvt_weights(const float* a, int na, unsigned short* ab,
                            const float* b, int nb, unsigned short* bb,
                            const float* c, int nc, unsigned short* cb,
                            const float* d, int nd, unsigned short* db) {
  int i = blockIdx.x * 256 + threadIdx.x;
  if (i < na) ab[i] = f2bf(a[i]);
  if (i < nb) bb[i] = f2bf(b[i]);
  if (i < nc) cb[i] = f2bf(c[i]);
  if (i < nd) db[i] = f2bf(d[i]);
}

// ---------------- K1: conv1(3->64)+relu, conv2(64->64)+relu, plus xx sums ---
__global__ __launch_bounds__(256) void conv12(
    const float* __restrict__ xin, const float* __restrict__ w1,
    const float* __restrict__ b1, const float* __restrict__ w2,
    const float* __restrict__ b2, float* __restrict__ h,
    float* __restrict__ hh, float* __restrict__ cc) {
  int wave = threadIdx.x >> 6, lane = threadIdx.x & 63;
  int p = blockIdx.x * 4 + wave;                    // grid 8192
  __shared__ float s_h1[4][64];
  const float* xp = xin + p * 3;
  float c0 = xp[0], c1 = xp[1], c2 = xp[2];
  float v = b1[lane] + w1[lane*3+0]*c0 + w1[lane*3+1]*c1 + w1[lane*3+2]*c2;
  s_h1[wave][lane] = fmaxf(v, 0.f);
  __syncthreads();
  float acc = b2[lane];
  const float* wr = w2 + lane * 64;
  #pragma unroll
  for (int c = 0; c < 64; c += 4) {
    floatx4 w4 = *(const floatx4*)(wr + c);
    acc += w4[0]*s_h1[wave][c]   + w4[1]*s_h1[wave][c+1]
         + w4[2]*s_h1[wave][c+2] + w4[3]*s_h1[wave][c+3];
  }
  acc = fmaxf(acc, 0.f);
  h[p*64 + lane] = acc;
  float sq = acc * acc;
  #pragma unroll
  for (int off = 32; off; off >>= 1) sq += __shfl_xor(sq, off, 64);
  if (lane == 0) { hh[p] = sq; cc[p] = c0*c0 + c1*c1 + c2*c2; }
}

// ---------------- K2: fused pairwise distance + batched top-20 ---------------
// 64 rows/block, m-tiles of 64. Compute threads (tr=t>>4, tm=t&15) hold the
// 4x4 score tile in REGISTERS (no dots round-trip) and push candidates passing
// the shared row-threshold tau into per-row LDS queues (cheap: atomic inc + 1
// store). After a barrier, ALL lanes drain together: owner (row=t>>2, sub=t&3)
// pops entries j=sub,sub+4,... and runs the expensive register-list insert --
// 64 inserts per wave-execution instead of 1 (kills the divergence-union cost
// that dominated R3: ~1728 solo insert bodies x ~300cyc = ~430us).
// tau = shfl-max over the 4 owners' list minima (provably <= row running 20th
// -> pruning safe). Queue cap 64 = max pushes/row/tile; drained every tile.
// Eviction by value only (exact fp32 ties among distinct points: measure-zero;
// only the neighbor SET matters downstream -- max over k).
template<int C>
__global__ __launch_bounds__(256) void knn_topk(
    const float* __restrict__ X, const float* __restrict__ XX,
    int* __restrict__ idx_out) {
  __shared__ float rowsT[C][68];
  __shared__ float mT[C][68];
  __shared__ float xxR[64];
  __shared__ float xxM[64];
  __shared__ float tau[64];
  __shared__ int   qn[64];
  __shared__ uint2 qv[64][64];        // 32 KB candidate queues
  int b = blockIdx.y;
  int r0 = blockIdx.x * 64;
  int t = threadIdx.x;
  const float* Xb = X + (size_t)b * NP * C;
  for (int e = t; e < C * 64; e += 256) {
    int r = e / C, c = e - r * C;
    rowsT[c][r] = Xb[(r0 + r) * C + c];
  }
  if (t < 64) {
    xxR[t] = XX[b * NP + r0 + t];
    tau[t] = -__builtin_inff();
    qn[t] = 0;
  }

  float lv[20]; int li[20];
  #pragma unroll
  for (int s = 0; s < 20; s++) { lv[s] = -__builtin_inff(); li[s] = 0x7fffffff; }
  float minval = -__builtin_inff(); int minpos = 0;

  int tm = t & 15, tr = t >> 4;         // compute mapping
  int row = t >> 2, sub = t & 3;        // selection mapping

  for (int mt = 0; mt < NP / 64; mt++) {
    int m0 = mt * 64;
    for (int e = t; e < C * 64; e += 256) {
      int r = e / C, c = e - r * C;
      mT[c][r] = Xb[(m0 + r) * C + c];
    }
    if (t < 64) xxM[t] = XX[b * NP + m0 + t];
    __syncthreads();                    // staging + prev drain complete
    float acc[4][4];
    #pragma unroll
    for (int i = 0; i < 4; i++)
      #pragma unroll
      for (int j = 0; j < 4; j++) acc[i][j] = 0.f;
    for (int c = 0; c < C; c++) {
      floatx4 av = *(floatx4*)&rowsT[c][tr * 4];
      floatx4 bv = *(floatx4*)&mT[c][tm * 4];
      #pragma unroll
      for (int i = 0; i < 4; i++)
        #pragma unroll
        for (int j = 0; j < 4; j++) acc[i][j] += av[i] * bv[j];
    }
    // score + push (values stay in registers; no dots LDS round-trip)
    #pragma unroll
    for (int i = 0; i < 4; i++) {
      int r = tr * 4 + i;
      float g = tau[r];                 // 16-lane broadcast read
      float xr = xxR[r];
      #pragma unroll
      for (int j = 0; j < 4; j++) {
        float v = 2.f * acc[i][j] - xr - xxM[tm*4 + j];
        if (v > g) {
          int slot = atomicAdd(&qn[r], 1);
          qv[r][slot] = make_uint2(__float_as_uint(v), (unsigned)(m0 + tm*4 + j));
        }
      }
    }
    __syncthreads();                    // pushes visible; mT free for restage
    // batched drain: every lane inserts simultaneously (union cost = max)
    int cnt = qn[row];
    for (int j = sub; j < cnt; j += 4) {
      uint2 e = qv[row][j];
      float v = __uint_as_float(e.x);
      if (v > minval) {
        int gi = (int)e.y;
        #pragma unroll
        for (int s = 0; s < 20; s++)
          if (s == minpos) { lv[s] = v; li[s] = gi; }
        minval = __builtin_inff();
        #pragma unroll
        for (int s = 0; s < 20; s++)
          if (lv[s] < minval) { minval = lv[s]; minpos = s; }
      }
    }
    if (sub == 0) qn[row] = 0;
    // race-free tau update: max of the 4 owners' minima (lanes 4r..4r+3)
    float m = minval;
    m = fmaxf(m, __shfl_xor(m, 1, 64));
    m = fmaxf(m, __shfl_xor(m, 2, 64));
    if (sub == 0) tau[row] = m;
  }
  // merge 4 per-thread lists -> row top-20 set (tie-break lower index)
  int base = (b * NP + r0 + row) * 20;
  for (int sel = 0; sel < 20; sel++) {
    float mybv = -__builtin_inff(); int mybi = 0x7fffffff, mybs = 0;
    #pragma unroll
    for (int s = 0; s < 20; s++) {
      bool better = lv[s] > mybv || (lv[s] == mybv && li[s] < mybi);
      if (better) { mybv = lv[s]; mybi = li[s]; mybs = s; }
    }
    float bv = mybv; int bi = mybi;
    float ov = __shfl_xor(bv, 1, 64); int oi = __shfl_xor(bi, 1, 64);
    if (ov > bv || (ov == bv && oi < bi)) { bv = ov; bi = oi; }
    ov = __shfl_xor(bv, 2, 64); oi = __shfl_xor(bi, 2, 64);
    if (ov > bv || (ov == bv && oi < bi)) { bv = ov; bi = oi; }
    if (sub == 0) idx_out[base + sel] = bi;
    if (bi == mybi) {                   // queue entries unique -> unique owner
      #pragma unroll
      for (int s = 0; s < 20; s++)
        if (s == mybs) { lv[s] = -__builtin_inff(); li[s] = 0x7fffffff; }
    }
  }
}

// ---------------- K3: graph_feature(h,idx1) -> dg1 -> max -> dg2 -> max ------
__global__ __launch_bounds__(256) void dg_stage(
    const float* __restrict__ h, const int* __restrict__ idx1,
    const unsigned short* __restrict__ w1b, const float* __restrict__ bia1,
    const unsigned short* __restrict__ w2b, const float* __restrict__ bia2,
    unsigned short* __restrict__ featb) {
  __shared__ unsigned short s_a[32][136];
  __shared__ unsigned short s_v[32][136];
  __shared__ int s_nb[20];
  int p = blockIdx.x;
  int b = p >> 12, n = p & 4095;
  int t = threadIdx.x;
  int lane = t & 63, wave = t >> 6;
  if (t < 20) s_nb[t] = idx1[p * 20 + t];
  __syncthreads();
  const float* hb = h + (size_t)b * NP * 64;
  const float* hc = hb + n * 64;
  for (int e = t; e < 2560; e += 256) {
    int k = e >> 7, c = e & 127;
    float v = (c < 64) ? (hb[s_nb[k] * 64 + c] - hc[c]) : hc[c - 64];
    s_a[k][c] = f2bf(v);
  }
  for (int e = t; e < 1536; e += 256) s_a[20 + (e >> 7)][e & 127] = 0;
  __syncthreads();
  int quad = lane >> 4, mrow = lane & 15;
  int nblock = wave * 32;
  floatx4 acc[2][2];
  #pragma unroll
  for (int i = 0; i < 2; i++)
    #pragma unroll
    for (int j = 0; j < 2; j++) acc[i][j] = (floatx4)0.f;
  #pragma unroll
  for (int ks = 0; ks < 4; ks++) {
    int k0 = ks * 32 + quad * 8;
    short8 a0 = *(short8*)&s_a[mrow][k0];
    short8 a1 = *(short8*)&s_a[16 + mrow][k0];
    short8 w0 = *(const short8*)(w1b + (nblock + mrow) * 128 + k0);
    short8 w1v = *(const short8*)(w1b + (nblock + 16 + mrow) * 128 + k0);
    acc[0][0] = mfma_bf16(a0, w0, acc[0][0]);
    acc[1][0] = mfma_bf16(a1, w0, acc[1][0]);
    acc[0][1] = mfma_bf16(a0, w1v, acc[0][1]);
    acc[1][1] = mfma_bf16(a1, w1v, acc[1][1]);
  }
  #pragma unroll
  for (int mt = 0; mt < 2; mt++)
    #pragma unroll
    for (int ns = 0; ns < 2; ns++)
      #pragma unroll
      for (int r = 0; r < 4; r++) {
        int m = mt * 16 + quad * 4 + r;
        int o = nblock + ns * 16 + mrow;
        s_v[m][o] = f2bf(fmaxf(acc[mt][ns][r] + bia1[o], 0.f));
      }
  __syncthreads();
  if (t < 128) {
    float mx = 0.f;
    for (int k = 0; k < 20; k++) mx = fmaxf(mx, bf2f(s_v[k][t]));
    featb[p * 512 + t] = f2bf(mx);
  }
  #pragma unroll
  for (int i = 0; i < 2; i++)
    #pragma unroll
    for (int j = 0; j < 2; j++) acc[i][j] = (floatx4)0.f;
  #pragma unroll
  for (int ks = 0; ks < 4; ks++) {
    int k0 = ks * 32 + quad * 8;
    short8 a0 = *(short8*)&s_v[mrow][k0];
    short8 a1 = *(short8*)&s_v[16 + mrow][k0];
    short8 w0 = *(const short8*)(w2b + (nblock + mrow) * 128 + k0);
    short8 w1v = *(const short8*)(w2b + (nblock + 16 + mrow) * 128 + k0);
    acc[0][0] = mfma_bf16(a0, w0, acc[0][0]);
    acc[1][0] = mfma_bf16(a1, w0, acc[1][0]);
    acc[0][1] = mfma_bf16(a0, w1v, acc[0][1]);
    acc[1][1] = mfma_bf16(a1, w1v, acc[1][1]);
  }
  float vmax[2] = {0.f, 0.f};
  #pragma unroll
  for (int mt = 0; mt < 2; mt++)
    #pragma unroll
    for (int ns = 0; ns < 2; ns++)
      #pragma unroll
      for (int r = 0; r < 4; r++) {
        int m = mt * 16 + quad * 4 + r;
        if (m < 20) {
          int o = nblock + ns * 16 + mrow;
          vmax[ns] = fmaxf(vmax[ns], fmaxf(acc[mt][ns][r] + bia2[o], 0.f));
        }
      }
  #pragma unroll
  for (int ns = 0; ns < 2; ns++) {
    float v = vmax[ns];
    v = fmaxf(v, __shfl_xor(v, 16, 64));
    v = fmaxf(v, __shfl_xor(v, 32, 64));
    if (lane < 16) featb[p * 512 + 128 + nblock + ns * 16 + lane] = f2bf(v);
  }
}

// ---------------- K4: graph_feature(x2,idx2) -> sn1 -> max -------------------
__global__ __launch_bounds__(256) void sn_stage(
    const int* __restrict__ idx2, const unsigned short* __restrict__ wb,
    const float* __restrict__ bias, unsigned short* __restrict__ featb) {
  __shared__ unsigned short s_a[32][264];
  __shared__ int s_nb[20];
  int p = blockIdx.x;
  int b = p >> 12;
  int t = threadIdx.x;
  int lane = t & 63, wave = t >> 6;
  if (t < 20) s_nb[t] = idx2[p * 20 + t];
  __syncthreads();
  const unsigned short* x2b = featb + (size_t)b * NP * 512 + 128;
  const unsigned short* x2c = featb + (size_t)p * 512 + 128;
  for (int e = t; e < 5120; e += 256) {
    int k = e >> 8, c = e & 255;
    float v = (c < 128) ? (bf2f(x2b[(size_t)s_nb[k] * 512 + c]) - bf2f(x2c[c]))
                        : bf2f(x2c[c - 128]);
    s_a[k][c] = f2bf(v);
  }
  for (int e = t; e < 3072; e += 256) s_a[20 + (e >> 8)][e & 255] = 0;
  __syncthreads();
  int quad = lane >> 4, mrow = lane & 15;
  int nblock = wave * 64;
  floatx4 acc[2][4];
  #pragma unroll
  for (int i = 0; i < 2; i++)
    #pragma unroll
    for (int j = 0; j < 4; j++) acc[i][j] = (floatx4)0.f;
  #pragma unroll
  for (int ks = 0; ks < 8; ks++) {
    int k0 = ks * 32 + quad * 8;
    short8 a0 = *(short8*)&s_a[mrow][k0];
    short8 a1 = *(short8*)&s_a[16 + mrow][k0];
    #pragma unroll
    for (int ns = 0; ns < 4; ns++) {
      short8 w = *(const short8*)(wb + (nblock + ns * 16 + mrow) * 256 + k0);
      acc[0][ns] = mfma_bf16(a0, w, acc[0][ns]);
      acc[1][ns] = mfma_bf16(a1, w, acc[1][ns]);
    }
  }
  float vmax[4] = {0.f, 0.f, 0.f, 0.f};
  #pragma unroll
  for (int mt = 0; mt < 2; mt++)
    #pragma unroll
    for (int ns = 0; ns < 4; ns++)
      #pragma unroll
      for (int r = 0; r < 4; r++) {
        int m = mt * 16 + quad * 4 + r;
        if (m < 20) {
          int o = nblock + ns * 16 + mrow;
          vmax[ns] = fmaxf(vmax[ns], fmaxf(acc[mt][ns][r] + bias[o], 0.f));
        }
      }
  #pragma unroll
  for (int ns = 0; ns < 4; ns++) {
    float v = vmax[ns];
    v = fmaxf(v, __shfl_xor(v, 16, 64));
    v = fmaxf(v, __shfl_xor(v, 32, 64));
    if (lane < 16) featb[p * 512 + 256 + nblock + ns * 16 + lane] = f2bf(v);
  }
}

// ---------------- K5: conv3 GEMM ---------------------------------------------
__global__ __launch_bounds__(256) void conv3_gemm(
    const unsigned short* __restrict__ w3b, const unsigned short* __restrict__ featb,
    const float* __restrict__ b3, float* __restrict__ out) {
  __shared__ unsigned short s_a[128][40];
  __shared__ unsigned short s_b[128][40];
  int o0 = blockIdx.x * 128, p0 = blockIdx.y * 128;
  int t = threadIdx.x, lane = t & 63, wave = t >> 6;
  int wy = wave >> 1, wx = wave & 1;
  int quad = lane >> 4, l15 = lane & 15;
  floatx4 acc[4][4];
  #pragma unroll
  for (int i = 0; i < 4; i++)
    #pragma unroll
    for (int j = 0; j < 4; j++) acc[i][j] = (floatx4)0.f;
  for (int kc = 0; kc < 16; kc++) {
    __syncthreads();
    for (int e = t; e < 512; e += 256) {
      int r = e >> 2, c8 = (e & 3) * 8;
      *(short8*)&s_a[r][c8] = *(const short8*)(w3b + (size_t)(o0 + r) * 512 + kc * 32 + c8);
    }
    for (int e = t; e < 512; e += 256) {
      int r = e >> 2, c8 = (e & 3) * 8;
      *(short8*)&s_b[r][c8] = *(const short8*)(featb + (size_t)(p0 + r) * 512 + kc * 32 + c8);
    }
    __syncthreads();
    int k0 = quad * 8;
    short8 af[4], bfr[4];
    #pragma unroll
    for (int i = 0; i < 4; i++) af[i] = *(short8*)&s_a[wy * 64 + i * 16 + l15][k0];
    #pragma unroll
    for (int j = 0; j < 4; j++) bfr[j] = *(short8*)&s_b[wx * 64 + j * 16 + l15][k0];
    #pragma unroll
    for (int i = 0; i < 4; i++)
      #pragma unroll
      for (int j = 0; j < 4; j++) acc[i][j] = mfma_bf16(af[i], bfr[j], acc[i][j]);
  }
  #pragma unroll
  for (int i = 0; i < 4; i++)
    #pragma unroll
    for (int j = 0; j < 4; j++) {
      int pl = p0 + wx * 64 + j * 16 + l15;
      int bI = pl >> 12, n = pl & 4095;
      #pragma unroll
      for (int r = 0; r < 4; r++) {
        int o = o0 + wy * 64 + i * 16 + quad * 4 + r;
        out[(size_t)(bI * 1024 + o) * 4096 + n] = fmaxf(acc[i][j][r] + b3[o], 0.f);
      }
    }
}

// ---------------- launcher ---------------------------------------------------
extern "C" void kernel_launch(void* const* d_in, const int* in_sizes, int n_in,
                              void* d_out, int out_size, void* d_ws, size_t ws_size,
                              hipStream_t stream) {
  const float* x    = (const float*)d_in[0];
  const float* w1   = (const float*)d_in[1];
  const float* b1   = (const float*)d_in[2];
  const float* w2   = (const float*)d_in[3];
  const float* b2   = (const float*)d_in[4];
  const float* wdg1 = (const float*)d_in[5];
  const float* bdg1 = (const float*)d_in[6];
  const float* wdg2 = (const float*)d_in[7];
  const float* bdg2 = (const float*)d_in[8];
  const float* wsn1 = (const float*)d_in[9];
  const float* bsn1 = (const float*)d_in[10];
  const float* w3   = (const float*)d_in[11];
  const float* b3   = (const float*)d_in[12];

  float* ws = (float*)d_ws;
  float* h  = ws;                           // 2,097,152
  float* hh = ws + 2097152;                 //    32,768
  float* cc = ws + 2129920;                 //    32,768
  int* idx1 = (int*)(ws + 2162688);         //   655,360
  int* idx2 = (int*)(ws + 2818048);         //   655,360
  unsigned short* featb = (unsigned short*)(ws + 3473408);   // 16,777,216 bf16
  unsigned short* wdg1b = (unsigned short*)(ws + 11862016);
  unsigned short* wdg2b = (unsigned short*)(ws + 11870208);
  unsigned short* wsn1b = (unsigned short*)(ws + 11878400);
  unsigned short* w3b   = (unsigned short*)(ws + 11911168);

  cvt_weights<<<2048, 256, 0, stream>>>(wdg1, 16384, wdg1b, wdg2, 16384, wdg2b,
                                        wsn1, 65536, wsn1b, w3, 524288, w3b);
  conv12<<<8192, 256, 0, stream>>>(x, w1, b1, w2, b2, h, hh, cc);
  knn_topk<64><<<dim3(64, 8), 256, 0, stream>>>(h, hh, idx1);
  knn_topk<3><<<dim3(64, 8), 256, 0, stream>>>(x, cc, idx2);
  dg_stage<<<32768, 256, 0, stream>>>(h, idx1, wdg1b, bdg1, wdg2b, bdg2, featb);
  sn_stage<<<32768, 256, 0, stream>>>(idx2, wsn1b, bsn1, featb);
  conv3_gemm<<<dim3(8, 256), 256, 0, stream>>>(w3b, featb, b3, (float*)d_out);
}

// Round 5
// 1745.845 us; speedup vs baseline: 7.9633x; 7.9633x over previous
//
#include <hip/hip_runtime.h>
#include <stdint.h>

// LPDNet forward on gfx950.
// Layout decisions:
//   h     : (B,N,64) fp32 rows  -> coalesced gather + fp32-exact knn distances
//   featb : (B,N,512) bf16 rows -> [x1 | x2 | x3], rows feed conv3 GEMM and x2 gather
//   idx1/idx2 : (B,N,20) int32
// bf16 everywhere in the conv path (fp32 accum); tolerance is 2% of max|ref|.

#define NB 8
#define NP 4096
#define NPTS (NB*NP)

typedef float  floatx4 __attribute__((ext_vector_type(4)));
typedef short  short8  __attribute__((ext_vector_type(8)));

__device__ __forceinline__ unsigned short f2bf(float f) {
  union { float f; uint32_t u; } v; v.f = f;
  uint32_t r = v.u + 0x7fffu + ((v.u >> 16) & 1u);   // RNE
  return (unsigned short)(r >> 16);
}
__device__ __forceinline__ float bf2f(unsigned short h) {
  union { uint32_t u; float f; } v; v.u = ((uint32_t)h) << 16;
  return v.f;
}

__device__ __forceinline__ floatx4 mfma_bf16(short8 a, short8 b, floatx4 c) {
  return __builtin_amdgcn_mfma_f32_16x16x32_bf16(a, b, c, 0, 0, 0);
}

// ---------------- K0: fp32 -> bf16 weight conversion (runs every launch) ----
__global__ void cvt_weights(const float* a, int na, unsigned short* ab,
                            const float* b, int nb, unsigned short* bb,
                            const float* c, int nc, unsigned short* cb,
                            const float* d, int nd, unsigned short* db) {
  int i = blockIdx.x * 256 + threadIdx.x;
  if (i < na) ab[i] = f2bf(a[i]);
  if (i < nb) bb[i] = f2bf(b[i]);
  if (i < nc) cb[i] = f2bf(c[i]);
  if (i < nd) db[i] = f2bf(d[i]);
}

// ---------------- K1: conv1(3->64)+relu, conv2(64->64)+relu, plus xx sums ---
__global__ __launch_bounds__(256) void conv12(
    const float* __restrict__ xin, const float* __restrict__ w1,
    const float* __restrict__ b1, const float* __restrict__ w2,
    const float* __restrict__ b2, float* __restrict__ h,
    float* __restrict__ hh, float* __restrict__ cc) {
  int wave = threadIdx.x >> 6, lane = threadIdx.x & 63;
  int p = blockIdx.x * 4 + wave;                    // grid 8192
  __shared__ float s_h1[4][64];
  const float* xp = xin + p * 3;
  float c0 = xp[0], c1 = xp[1], c2 = xp[2];
  float v = b1[lane] + w1[lane*3+0]*c0 + w1[lane*3+1]*c1 + w1[lane*3+2]*c2;
  s_h1[wave][lane] = fmaxf(v, 0.f);
  __syncthreads();
  float acc = b2[lane];
  const float* wr = w2 + lane * 64;
  #pragma unroll
  for (int c = 0; c < 64; c += 4) {
    floatx4 w4 = *(const floatx4*)(wr + c);
    acc += w4[0]*s_h1[wave][c]   + w4[1]*s_h1[wave][c+1]
         + w4[2]*s_h1[wave][c+2] + w4[3]*s_h1[wave][c+3];
  }
  acc = fmaxf(acc, 0.f);
  h[p*64 + lane] = acc;
  float sq = acc * acc;
  #pragma unroll
  for (int off = 32; off; off >>= 1) sq += __shfl_xor(sq, off, 64);
  if (lane == 0) { hh[p] = sq; cc[p] = c0*c0 + c1*c1 + c2*c2; }
}

// ---------------- K2: fused pairwise distance + ballot-batched top-20 --------
// 64 rows/block, m-tiles of 64. Compute: 256 threads = 4x16 grid of 4x4 fp32
// register tiles -> dots LDS. Selection: 4 threads per row (row=t>>2, sub=t&3),
// register top-20 lists gated by shared row-threshold tau (safe pruning, R3-
// proven). NEW vs R3: candidates are first collected into a 16-bit register
// mask (cheap compares, no divergence), then drained in a wave-synchronized
// bounded loop -- all lanes with pending candidates run the expensive insert
// body SIMULTANEOUSLY, so the wave pays max(per-lane cands) ~2-3 instead of
// sum ~13-16 body executions per tile. unroll(disable) on the drain loop keeps
// the insert body single-copy (R4's spill came from compiler-duplicating it:
// VGPR 68->256, 19.7 GB scratch FETCH).
// Eviction by value only (exact fp32 ties among distinct points: measure-zero;
// only the neighbor SET matters downstream -- max over k).
template<int C>
__global__ __launch_bounds__(256) void knn_topk(
    const float* __restrict__ X, const float* __restrict__ XX,
    int* __restrict__ idx_out) {
  __shared__ float rowsT[C][68];
  __shared__ float mT[C][68];
  __shared__ float dots[64][68];   // pad 68: float4-aligned rows
  __shared__ float xxR[64];
  __shared__ float xxM[64];
  __shared__ float tau[64];
  int b = blockIdx.y;
  int r0 = blockIdx.x * 64;
  int t = threadIdx.x;
  const float* Xb = X + (size_t)b * NP * C;
  for (int e = t; e < C * 64; e += 256) {
    int r = e / C, c = e - r * C;
    rowsT[c][r] = Xb[(r0 + r) * C + c];
  }
  if (t < 64) { xxR[t] = XX[b * NP + r0 + t]; tau[t] = -__builtin_inff(); }

  float lv[20]; int li[20];
  #pragma unroll
  for (int s = 0; s < 20; s++) { lv[s] = -__builtin_inff(); li[s] = 0x7fffffff; }
  float minval = -__builtin_inff(); int minpos = 0;

  int tm = t & 15, tr = t >> 4;         // compute mapping
  int row = t >> 2, sub = t & 3;        // selection mapping

  for (int mt = 0; mt < NP / 64; mt++) {
    int m0 = mt * 64;
    for (int e = t; e < C * 64; e += 256) {
      int r = e / C, c = e - r * C;
      mT[c][r] = Xb[(m0 + r) * C + c];
    }
    if (t < 64) xxM[t] = XX[b * NP + m0 + t];
    __syncthreads();                       // staging done; prior select done
    float acc[4][4];
    #pragma unroll
    for (int i = 0; i < 4; i++)
      #pragma unroll
      for (int j = 0; j < 4; j++) acc[i][j] = 0.f;
    for (int c = 0; c < C; c++) {
      floatx4 av = *(floatx4*)&rowsT[c][tr * 4];
      floatx4 bv = *(floatx4*)&mT[c][tm * 4];
      #pragma unroll
      for (int i = 0; i < 4; i++)
        #pragma unroll
        for (int j = 0; j < 4; j++) acc[i][j] += av[i] * bv[j];
    }
    #pragma unroll
    for (int i = 0; i < 4; i++) {
      floatx4 sv;
      #pragma unroll
      for (int j = 0; j < 4; j++)
        sv[j] = 2.f * acc[i][j] - xxR[tr*4 + i] - xxM[tm*4 + j];
      *(floatx4*)&dots[tr*4 + i][tm*4] = sv;
    }
    __syncthreads();                       // dots ready
    // ---- phase 1: register-compare 16 candidates -> bitmask (no divergence)
    float gate = fmaxf(minval, tau[row]);
    floatx4 dv0 = *(floatx4*)&dots[row][sub * 16];
    floatx4 dv1 = *(floatx4*)&dots[row][sub * 16 + 4];
    floatx4 dv2 = *(floatx4*)&dots[row][sub * 16 + 8];
    floatx4 dv3 = *(floatx4*)&dots[row][sub * 16 + 12];
    uint32_t mask = 0;
    #pragma unroll
    for (int j = 0; j < 4; j++) {
      if (dv0[j] > gate) mask |= 1u << j;
      if (dv1[j] > gate) mask |= 1u << (4 + j);
      if (dv2[j] > gate) mask |= 1u << (8 + j);
      if (dv3[j] > gate) mask |= 1u << (12 + j);
    }
    // ---- phase 2: wave-synchronized drain (parallel insert bodies)
    #pragma clang loop unroll(disable)
    for (int round = 0; round < 16; round++) {
      if (!__any(mask != 0)) break;
      if (mask) {
        int i = __builtin_ctz(mask); mask &= mask - 1;
        float v = dots[row][sub * 16 + i];   // LDS reload (never reg-indexed)
        if (v > minval) {
          int gi = m0 + sub * 16 + i;
          #pragma unroll
          for (int s = 0; s < 20; s++)
            if (s == minpos) { lv[s] = v; li[s] = gi; }
          minval = __builtin_inff();
          #pragma unroll
          for (int s = 0; s < 20; s++)
            if (lv[s] < minval) { minval = lv[s]; minpos = s; }
        }
      }
    }
    // publish my list-min as a row lower bound (races only loosen tau: safe)
    tau[row] = fmaxf(tau[row], minval);
  }
  // merge 4 per-thread lists -> row top-20 set (tie-break lower index)
  int base = (b * NP + r0 + row) * 20;
  for (int sel = 0; sel < 20; sel++) {
    float mybv = -__builtin_inff(); int mybi = 0x7fffffff, mybs = 0;
    #pragma unroll
    for (int s = 0; s < 20; s++) {
      bool better = lv[s] > mybv || (lv[s] == mybv && li[s] < mybi);
      if (better) { mybv = lv[s]; mybi = li[s]; mybs = s; }
    }
    float bv = mybv; int bi = mybi;
    float ov = __shfl_xor(bv, 1, 64); int oi = __shfl_xor(bi, 1, 64);
    if (ov > bv || (ov == bv && oi < bi)) { bv = ov; bi = oi; }
    ov = __shfl_xor(bv, 2, 64); oi = __shfl_xor(bi, 2, 64);
    if (ov > bv || (ov == bv && oi < bi)) { bv = ov; bi = oi; }
    if (sub == 0) idx_out[base + sel] = bi;
    if (bi == mybi) {                      // column sets disjoint -> unique owner
      #pragma unroll
      for (int s = 0; s < 20; s++)
        if (s == mybs) { lv[s] = -__builtin_inff(); li[s] = 0x7fffffff; }
    }
  }
}

// ---------------- K3: graph_feature(h,idx1) -> dg1 -> max -> dg2 -> max ------
__global__ __launch_bounds__(256) void dg_stage(
    const float* __restrict__ h, const int* __restrict__ idx1,
    const unsigned short* __restrict__ w1b, const float* __restrict__ bia1,
    const unsigned short* __restrict__ w2b, const float* __restrict__ bia2,
    unsigned short* __restrict__ featb) {
  __shared__ unsigned short s_a[32][136];
  __shared__ unsigned short s_v[32][136];
  __shared__ int s_nb[20];
  int p = blockIdx.x;
  int b = p >> 12, n = p & 4095;
  int t = threadIdx.x;
  int lane = t & 63, wave = t >> 6;
  if (t < 20) s_nb[t] = idx1[p * 20 + t];
  __syncthreads();
  const float* hb = h + (size_t)b * NP * 64;
  const float* hc = hb + n * 64;
  for (int e = t; e < 2560; e += 256) {
    int k = e >> 7, c = e & 127;
    float v = (c < 64) ? (hb[s_nb[k] * 64 + c] - hc[c]) : hc[c - 64];
    s_a[k][c] = f2bf(v);
  }
  for (int e = t; e < 1536; e += 256) s_a[20 + (e >> 7)][e & 127] = 0;
  __syncthreads();
  int quad = lane >> 4, mrow = lane & 15;
  int nblock = wave * 32;
  floatx4 acc[2][2];
  #pragma unroll
  for (int i = 0; i < 2; i++)
    #pragma unroll
    for (int j = 0; j < 2; j++) acc[i][j] = (floatx4)0.f;
  #pragma unroll
  for (int ks = 0; ks < 4; ks++) {
    int k0 = ks * 32 + quad * 8;
    short8 a0 = *(short8*)&s_a[mrow][k0];
    short8 a1 = *(short8*)&s_a[16 + mrow][k0];
    short8 w0 = *(const short8*)(w1b + (nblock + mrow) * 128 + k0);
    short8 w1v = *(const short8*)(w1b + (nblock + 16 + mrow) * 128 + k0);
    acc[0][0] = mfma_bf16(a0, w0, acc[0][0]);
    acc[1][0] = mfma_bf16(a1, w0, acc[1][0]);
    acc[0][1] = mfma_bf16(a0, w1v, acc[0][1]);
    acc[1][1] = mfma_bf16(a1, w1v, acc[1][1]);
  }
  #pragma unroll
  for (int mt = 0; mt < 2; mt++)
    #pragma unroll
    for (int ns = 0; ns < 2; ns++)
      #pragma unroll
      for (int r = 0; r < 4; r++) {
        int m = mt * 16 + quad * 4 + r;
        int o = nblock + ns * 16 + mrow;
        s_v[m][o] = f2bf(fmaxf(acc[mt][ns][r] + bia1[o], 0.f));
      }
  __syncthreads();
  if (t < 128) {
    float mx = 0.f;
    for (int k = 0; k < 20; k++) mx = fmaxf(mx, bf2f(s_v[k][t]));
    featb[p * 512 + t] = f2bf(mx);
  }
  #pragma unroll
  for (int i = 0; i < 2; i++)
    #pragma unroll
    for (int j = 0; j < 2; j++) acc[i][j] = (floatx4)0.f;
  #pragma unroll
  for (int ks = 0; ks < 4; ks++) {
    int k0 = ks * 32 + quad * 8;
    short8 a0 = *(short8*)&s_v[mrow][k0];
    short8 a1 = *(short8*)&s_v[16 + mrow][k0];
    short8 w0 = *(const short8*)(w2b + (nblock + mrow) * 128 + k0);
    short8 w1v = *(const short8*)(w2b + (nblock + 16 + mrow) * 128 + k0);
    acc[0][0] = mfma_bf16(a0, w0, acc[0][0]);
    acc[1][0] = mfma_bf16(a1, w0, acc[1][0]);
    acc[0][1] = mfma_bf16(a0, w1v, acc[0][1]);
    acc[1][1] = mfma_bf16(a1, w1v, acc[1][1]);
  }
  float vmax[2] = {0.f, 0.f};
  #pragma unroll
  for (int mt = 0; mt < 2; mt++)
    #pragma unroll
    for (int ns = 0; ns < 2; ns++)
      #pragma unroll
      for (int r = 0; r < 4; r++) {
        int m = mt * 16 + quad * 4 + r;
        if (m < 20) {
          int o = nblock + ns * 16 + mrow;
          vmax[ns] = fmaxf(vmax[ns], fmaxf(acc[mt][ns][r] + bia2[o], 0.f));
        }
      }
  #pragma unroll
  for (int ns = 0; ns < 2; ns++) {
    float v = vmax[ns];
    v = fmaxf(v, __shfl_xor(v, 16, 64));
    v = fmaxf(v, __shfl_xor(v, 32, 64));
    if (lane < 16) featb[p * 512 + 128 + nblock + ns * 16 + lane] = f2bf(v);
  }
}

// ---------------- K4: graph_feature(x2,idx2) -> sn1 -> max -------------------
__global__ __launch_bounds__(256) void sn_stage(
    const int* __restrict__ idx2, const unsigned short* __restrict__ wb,
    const float* __restrict__ bias, unsigned short* __restrict__ featb) {
  __shared__ unsigned short s_a[32][264];
  __shared__ int s_nb[20];
  int p = blockIdx.x;
  int b = p >> 12;
  int t = threadIdx.x;
  int lane = t & 63, wave = t >> 6;
  if (t < 20) s_nb[t] = idx2[p * 20 + t];
  __syncthreads();
  const unsigned short* x2b = featb + (size_t)b * NP * 512 + 128;
  const unsigned short* x2c = featb + (size_t)p * 512 + 128;
  for (int e = t; e < 5120; e += 256) {
    int k = e >> 8, c = e & 255;
    float v = (c < 128) ? (bf2f(x2b[(size_t)s_nb[k] * 512 + c]) - bf2f(x2c[c]))
                        : bf2f(x2c[c - 128]);
    s_a[k][c] = f2bf(v);
  }
  for (int e = t; e < 3072; e += 256) s_a[20 + (e >> 8)][e & 255] = 0;
  __syncthreads();
  int quad = lane >> 4, mrow = lane & 15;
  int nblock = wave * 64;
  floatx4 acc[2][4];
  #pragma unroll
  for (int i = 0; i < 2; i++)
    #pragma unroll
    for (int j = 0; j < 4; j++) acc[i][j] = (floatx4)0.f;
  #pragma unroll
  for (int ks = 0; ks < 8; ks++) {
    int k0 = ks * 32 + quad * 8;
    short8 a0 = *(short8*)&s_a[mrow][k0];
    short8 a1 = *(short8*)&s_a[16 + mrow][k0];
    #pragma unroll
    for (int ns = 0; ns < 4; ns++) {
      short8 w = *(const short8*)(wb + (nblock + ns * 16 + mrow) * 256 + k0);
      acc[0][ns] = mfma_bf16(a0, w, acc[0][ns]);
      acc[1][ns] = mfma_bf16(a1, w, acc[1][ns]);
    }
  }
  float vmax[4] = {0.f, 0.f, 0.f, 0.f};
  #pragma unroll
  for (int mt = 0; mt < 2; mt++)
    #pragma unroll
    for (int ns = 0; ns < 4; ns++)
      #pragma unroll
      for (int r = 0; r < 4; r++) {
        int m = mt * 16 + quad * 4 + r;
        if (m < 20) {
          int o = nblock + ns * 16 + mrow;
          vmax[ns] = fmaxf(vmax[ns], fmaxf(acc[mt][ns][r] + bias[o], 0.f));
        }
      }
  #pragma unroll
  for (int ns = 0; ns < 4; ns++) {
    float v = vmax[ns];
    v = fmaxf(v, __shfl_xor(v, 16, 64));
    v = fmaxf(v, __shfl_xor(v, 32, 64));
    if (lane < 16) featb[p * 512 + 256 + nblock + ns * 16 + lane] = f2bf(v);
  }
}

// ---------------- K5: conv3 GEMM ---------------------------------------------
__global__ __launch_bounds__(256) void conv3_gemm(
    const unsigned short* __restrict__ w3b, const unsigned short* __restrict__ featb,
    const float* __restrict__ b3, float* __restrict__ out) {
  __shared__ unsigned short s_a[128][40];
  __shared__ unsigned short s_b[128][40];
  int o0 = blockIdx.x * 128, p0 = blockIdx.y * 128;
  int t = threadIdx.x, lane = t & 63, wave = t >> 6;
  int wy = wave >> 1, wx = wave & 1;
  int quad = lane >> 4, l15 = lane & 15;
  floatx4 acc[4][4];
  #pragma unroll
  for (int i = 0; i < 4; i++)
    #pragma unroll
    for (int j = 0; j < 4; j++) acc[i][j] = (floatx4)0.f;
  for (int kc = 0; kc < 16; kc++) {
    __syncthreads();
    for (int e = t; e < 512; e += 256) {
      int r = e >> 2, c8 = (e & 3) * 8;
      *(short8*)&s_a[r][c8] = *(const short8*)(w3b + (size_t)(o0 + r) * 512 + kc * 32 + c8);
    }
    for (int e = t; e < 512; e += 256) {
      int r = e >> 2, c8 = (e & 3) * 8;
      *(short8*)&s_b[r][c8] = *(const short8*)(featb + (size_t)(p0 + r) * 512 + kc * 32 + c8);
    }
    __syncthreads();
    int k0 = quad * 8;
    short8 af[4], bfr[4];
    #pragma unroll
    for (int i = 0; i < 4; i++) af[i] = *(short8*)&s_a[wy * 64 + i * 16 + l15][k0];
    #pragma unroll
    for (int j = 0; j < 4; j++) bfr[j] = *(short8*)&s_b[wx * 64 + j * 16 + l15][k0];
    #pragma unroll
    for (int i = 0; i < 4; i++)
      #pragma unroll
      for (int j = 0; j < 4; j++) acc[i][j] = mfma_bf16(af[i], bfr[j], acc[i][j]);
  }
  #pragma unroll
  for (int i = 0; i < 4; i++)
    #pragma unroll
    for (int j = 0; j < 4; j++) {
      int pl = p0 + wx * 64 + j * 16 + l15;
      int bI = pl >> 12, n = pl & 4095;
      #pragma unroll
      for (int r = 0; r < 4; r++) {
        int o = o0 + wy * 64 + i * 16 + quad * 4 + r;
        out[(size_t)(bI * 1024 + o) * 4096 + n] = fmaxf(acc[i][j][r] + b3[o], 0.f);
      }
    }
}

// ---------------- launcher ---------------------------------------------------
extern "C" void kernel_launch(void* const* d_in, const int* in_sizes, int n_in,
                              void* d_out, int out_size, void* d_ws, size_t ws_size,
                              hipStream_t stream) {
  const float* x    = (const float*)d_in[0];
  const float* w1   = (const float*)d_in[1];
  const float* b1   = (const float*)d_in[2];
  const float* w2   = (const float*)d_in[3];
  const float* b2   = (const float*)d_in[4];
  const float* wdg1 = (const float*)d_in[5];
  const float* bdg1 = (const float*)d_in[6];
  const float* wdg2 = (const float*)d_in[7];
  const float* bdg2 = (const float*)d_in[8];
  const float* wsn1 = (const float*)d_in[9];
  const float* bsn1 = (const float*)d_in[10];
  const float* w3   = (const float*)d_in[11];
  const float* b3   = (const float*)d_in[12];

  float* ws = (float*)d_ws;
  float* h  = ws;                           // 2,097,152
  float* hh = ws + 2097152;                 //    32,768
  float* cc = ws + 2129920;                 //    32,768
  int* idx1 = (int*)(ws + 2162688);         //   655,360
  int* idx2 = (int*)(ws + 2818048);         //   655,360
  unsigned short* featb = (unsigned short*)(ws + 3473408);   // 16,777,216 bf16
  unsigned short* wdg1b = (unsigned short*)(ws + 11862016);
  unsigned short* wdg2b = (unsigned short*)(ws + 11870208);
  unsigned short* wsn1b = (unsigned short*)(ws + 11878400);
  unsigned short* w3b   = (unsigned short*)(ws + 11911168);

  cvt_weights<<<2048, 256, 0, stream>>>(wdg1, 16384, wdg1b, wdg2, 16384, wdg2b,
                                        wsn1, 65536, wsn1b, w3, 524288, w3b);
  conv12<<<8192, 256, 0, stream>>>(x, w1, b1, w2, b2, h, hh, cc);
  knn_topk<64><<<dim3(64, 8), 256, 0, stream>>>(h, hh, idx1);
  knn_topk<3><<<dim3(64, 8), 256, 0, stream>>>(x, cc, idx2);
  dg_stage<<<32768, 256, 0, stream>>>(h, idx1, wdg1b, bdg1, wdg2b, bdg2, featb);
  sn_stage<<<32768, 256, 0, stream>>>(idx2, wsn1b, bsn1, featb);
  conv3_gemm<<<dim3(8, 256), 256, 0, stream>>>(w3b, featb, b3, (float*)d_out);
}

// Round 6
// 1241.110 us; speedup vs baseline: 11.2018x; 1.4067x over previous
//
#include <hip/hip_runtime.h>
#include <stdint.h>

// LPDNet forward on gfx950.
// Layout decisions:
//   h     : (B,N,64) fp32 rows  -> fp32-exact knn distances
//   hb16  : (B,N,64) bf16 rows  -> pure-copy gather for dg_stage
//   featb : (B,N,512) bf16 rows -> [x1 | x2 | x3]; feeds conv3 GEMM and x2 gather
//   idx1/idx2 : (B,N,20) int32
// Graph-conv trick: W·[nbr-ctr | ctr] == W'·[nbr | ctr] with W' = [Wn | Wc-Wn]
// (transformed once in cvt_weights) -> gather staging is pure short8 copies.
// bf16 conv path (fp32 accum); tolerance is 2% of max|ref|.

#define NB 8
#define NP 4096
#define NPTS (NB*NP)

typedef float  floatx4 __attribute__((ext_vector_type(4)));
typedef short  short8  __attribute__((ext_vector_type(8)));

__device__ __forceinline__ unsigned short f2bf(float f) {
  union { float f; uint32_t u; } v; v.f = f;
  uint32_t r = v.u + 0x7fffu + ((v.u >> 16) & 1u);   // RNE
  return (unsigned short)(r >> 16);
}
__device__ __forceinline__ float bf2f(unsigned short h) {
  union { uint32_t u; float f; } v; v.u = ((uint32_t)h) << 16;
  return v.f;
}

__device__ __forceinline__ floatx4 mfma_bf16(short8 a, short8 b, floatx4 c) {
  return __builtin_amdgcn_mfma_f32_16x16x32_bf16(a, b, c, 0, 0, 0);
}

// ---------------- K0: weight conversion + graph-fold transform ---------------
__global__ void cvt_weights(const float* wdg1, unsigned short* wdg1b,
                            const float* wdg2, unsigned short* wdg2b,
                            const float* wsn1, unsigned short* wsn1b,
                            const float* w3, unsigned short* w3b) {
  int i = blockIdx.x * 256 + threadIdx.x;
  if (i < 16384) {                       // wdg1' = [Wn | Wc-Wn], C=64
    int c = i & 127;
    wdg1b[i] = f2bf(wdg1[i] - (c >= 64 ? wdg1[i - 64] : 0.f));
  }
  if (i < 16384) wdg2b[i] = f2bf(wdg2[i]);
  if (i < 65536) {                       // wsn1' = [Wn | Wc-Wn], C=128
    int c = i & 255;
    wsn1b[i] = f2bf(wsn1[i] - (c >= 128 ? wsn1[i - 128] : 0.f));
  }
  if (i < 524288) w3b[i] = f2bf(w3[i]);
}

// ---------------- K1: conv1+relu, conv2+relu, h fp32 + bf16, xx sums ---------
__global__ __launch_bounds__(256) void conv12(
    const float* __restrict__ xin, const float* __restrict__ w1,
    const float* __restrict__ b1, const float* __restrict__ w2,
    const float* __restrict__ b2, float* __restrict__ h,
    unsigned short* __restrict__ hb16,
    float* __restrict__ hh, float* __restrict__ cc) {
  int wave = threadIdx.x >> 6, lane = threadIdx.x & 63;
  int p = blockIdx.x * 4 + wave;                    // grid 8192
  __shared__ float s_h1[4][64];
  const float* xp = xin + p * 3;
  float c0 = xp[0], c1 = xp[1], c2 = xp[2];
  float v = b1[lane] + w1[lane*3+0]*c0 + w1[lane*3+1]*c1 + w1[lane*3+2]*c2;
  s_h1[wave][lane] = fmaxf(v, 0.f);
  __syncthreads();
  float acc = b2[lane];
  const float* wr = w2 + lane * 64;
  #pragma unroll
  for (int c = 0; c < 64; c += 4) {
    floatx4 w4 = *(const floatx4*)(wr + c);
    acc += w4[0]*s_h1[wave][c]   + w4[1]*s_h1[wave][c+1]
         + w4[2]*s_h1[wave][c+2] + w4[3]*s_h1[wave][c+3];
  }
  acc = fmaxf(acc, 0.f);
  h[p*64 + lane] = acc;
  hb16[p*64 + lane] = f2bf(acc);
  float sq = acc * acc;
  #pragma unroll
  for (int off = 32; off; off >>= 1) sq += __shfl_xor(sq, off, 64);
  if (lane == 0) { hh[p] = sq; cc[p] = c0*c0 + c1*c1 + c2*c2; }
}

// ---------------- K2: fused pairwise distance + ballot-batched top-20 --------
// (R5-proven structure: register top-20 + shared tau gate + wave-synchronized
// ballot drain; unroll(disable) keeps insert body single-copy = no spill.)
template<int C>
__global__ __launch_bounds__(256) void knn_topk(
    const float* __restrict__ X, const float* __restrict__ XX,
    int* __restrict__ idx_out) {
  __shared__ float rowsT[C][68];
  __shared__ float mT[C][68];
  __shared__ float dots[64][68];
  __shared__ float xxR[64];
  __shared__ float xxM[64];
  __shared__ float tau[64];
  int b = blockIdx.y;
  int r0 = blockIdx.x * 64;
  int t = threadIdx.x;
  const float* Xb = X + (size_t)b * NP * C;
  for (int e = t; e < C * 64; e += 256) {
    int r = e / C, c = e - r * C;
    rowsT[c][r] = Xb[(r0 + r) * C + c];
  }
  if (t < 64) { xxR[t] = XX[b * NP + r0 + t]; tau[t] = -__builtin_inff(); }

  float lv[20]; int li[20];
  #pragma unroll
  for (int s = 0; s < 20; s++) { lv[s] = -__builtin_inff(); li[s] = 0x7fffffff; }
  float minval = -__builtin_inff(); int minpos = 0;

  int tm = t & 15, tr = t >> 4;
  int row = t >> 2, sub = t & 3;

  for (int mt = 0; mt < NP / 64; mt++) {
    int m0 = mt * 64;
    for (int e = t; e < C * 64; e += 256) {
      int r = e / C, c = e - r * C;
      mT[c][r] = Xb[(m0 + r) * C + c];
    }
    if (t < 64) xxM[t] = XX[b * NP + m0 + t];
    __syncthreads();
    float acc[4][4];
    #pragma unroll
    for (int i = 0; i < 4; i++)
      #pragma unroll
      for (int j = 0; j < 4; j++) acc[i][j] = 0.f;
    for (int c = 0; c < C; c++) {
      floatx4 av = *(floatx4*)&rowsT[c][tr * 4];
      floatx4 bv = *(floatx4*)&mT[c][tm * 4];
      #pragma unroll
      for (int i = 0; i < 4; i++)
        #pragma unroll
        for (int j = 0; j < 4; j++) acc[i][j] += av[i] * bv[j];
    }
    #pragma unroll
    for (int i = 0; i < 4; i++) {
      floatx4 sv;
      #pragma unroll
      for (int j = 0; j < 4; j++)
        sv[j] = 2.f * acc[i][j] - xxR[tr*4 + i] - xxM[tm*4 + j];
      *(floatx4*)&dots[tr*4 + i][tm*4] = sv;
    }
    __syncthreads();
    float gate = fmaxf(minval, tau[row]);
    floatx4 dv0 = *(floatx4*)&dots[row][sub * 16];
    floatx4 dv1 = *(floatx4*)&dots[row][sub * 16 + 4];
    floatx4 dv2 = *(floatx4*)&dots[row][sub * 16 + 8];
    floatx4 dv3 = *(floatx4*)&dots[row][sub * 16 + 12];
    uint32_t mask = 0;
    #pragma unroll
    for (int j = 0; j < 4; j++) {
      if (dv0[j] > gate) mask |= 1u << j;
      if (dv1[j] > gate) mask |= 1u << (4 + j);
      if (dv2[j] > gate) mask |= 1u << (8 + j);
      if (dv3[j] > gate) mask |= 1u << (12 + j);
    }
    #pragma clang loop unroll(disable)
    for (int round = 0; round < 16; round++) {
      if (!__any(mask != 0)) break;
      if (mask) {
        int i = __builtin_ctz(mask); mask &= mask - 1;
        float v = dots[row][sub * 16 + i];
        if (v > minval) {
          int gi = m0 + sub * 16 + i;
          #pragma unroll
          for (int s = 0; s < 20; s++)
            if (s == minpos) { lv[s] = v; li[s] = gi; }
          minval = __builtin_inff();
          #pragma unroll
          for (int s = 0; s < 20; s++)
            if (lv[s] < minval) { minval = lv[s]; minpos = s; }
        }
      }
    }
    tau[row] = fmaxf(tau[row], minval);
  }
  int base = (b * NP + r0 + row) * 20;
  for (int sel = 0; sel < 20; sel++) {
    float mybv = -__builtin_inff(); int mybi = 0x7fffffff, mybs = 0;
    #pragma unroll
    for (int s = 0; s < 20; s++) {
      bool better = lv[s] > mybv || (lv[s] == mybv && li[s] < mybi);
      if (better) { mybv = lv[s]; mybi = li[s]; mybs = s; }
    }
    float bv = mybv; int bi = mybi;
    float ov = __shfl_xor(bv, 1, 64); int oi = __shfl_xor(bi, 1, 64);
    if (ov > bv || (ov == bv && oi < bi)) { bv = ov; bi = oi; }
    ov = __shfl_xor(bv, 2, 64); oi = __shfl_xor(bi, 2, 64);
    if (ov > bv || (ov == bv && oi < bi)) { bv = ov; bi = oi; }
    if (sub == 0) idx_out[base + sel] = bi;
    if (bi == mybi) {
      #pragma unroll
      for (int s = 0; s < 20; s++)
        if (s == mybs) { lv[s] = -__builtin_inff(); li[s] = 0x7fffffff; }
    }
  }
}

// ---------------- K3: dg stage, 4 points/block, M=80 (zero padding) ----------
// A = [h_nbr | h_ctr] (pure bf16 copies; subtraction folded into w1b').
// dg1 -> s_v -> x1 scan; dg2 (A=s_v) -> relu into s_a (reused) -> x2 scan.
__global__ __launch_bounds__(256) void dg_stage(
    const unsigned short* __restrict__ hb16, const int* __restrict__ idx1,
    const unsigned short* __restrict__ w1b, const float* __restrict__ bia1,
    const unsigned short* __restrict__ w2b, const float* __restrict__ bia2,
    unsigned short* __restrict__ featb) {
  __shared__ unsigned short s_a[80][136];   // row stride 272 B (16B-aligned)
  __shared__ unsigned short s_v[80][136];
  __shared__ int s_nbf[80];
  int p0 = blockIdx.x * 4;                  // grid 8192; 4 pts share batch b
  int b = p0 >> 12, n0 = p0 & 4095;
  int t = threadIdx.x;
  int lane = t & 63, wave = t >> 6;
  if (t < 80) s_nbf[t] = idx1[p0 * 20 + t];
  __syncthreads();
  const unsigned short* hbb = hb16 + (size_t)b * NP * 64;
  {
    int cc = (t & 15) * 8;                  // uniform per-thread across iters
    int r00 = t >> 4;
    #pragma unroll
    for (int it = 0; it < 5; it++) {
      int row = r00 + it * 16;
      const unsigned short* src = (cc < 64)
        ? hbb + (size_t)s_nbf[row] * 64 + cc
        : hbb + (size_t)(n0 + row / 20) * 64 + (cc - 64);
      *(short8*)&s_a[row][cc] = *(const short8*)src;
    }
  }
  __syncthreads();
  int quad = lane >> 4, mrow = lane & 15;
  int nblock = wave * 32;
  // ---- dg1: A=s_a(80x128), W=w1b' ----
  {
    floatx4 acc[5][2];
    #pragma unroll
    for (int mt = 0; mt < 5; mt++) { acc[mt][0] = (floatx4)0.f; acc[mt][1] = (floatx4)0.f; }
    #pragma unroll
    for (int ks = 0; ks < 4; ks++) {
      int k0 = ks * 32 + quad * 8;
      short8 w0 = *(const short8*)(w1b + (nblock + mrow) * 128 + k0);
      short8 w1v = *(const short8*)(w1b + (nblock + 16 + mrow) * 128 + k0);
      #pragma unroll
      for (int mt = 0; mt < 5; mt++) {
        short8 a = *(short8*)&s_a[mt * 16 + mrow][k0];
        acc[mt][0] = mfma_bf16(a, w0, acc[mt][0]);
        acc[mt][1] = mfma_bf16(a, w1v, acc[mt][1]);
      }
    }
    #pragma unroll
    for (int ns = 0; ns < 2; ns++) {
      int o = nblock + ns * 16 + mrow;
      float bz = bia1[o];
      #pragma unroll
      for (int mt = 0; mt < 5; mt++)
        #pragma unroll
        for (int r = 0; r < 4; r++)
          s_v[mt * 16 + quad * 4 + r][o] = f2bf(fmaxf(acc[mt][ns][r] + bz, 0.f));
    }
  }
  __syncthreads();                          // s_v ready; all s_a reads done
  // ---- x1 = max_k dg1 ----
  #pragma unroll
  for (int it = 0; it < 2; it++) {
    int e = t + it * 256;                   // 512 outputs
    int pt = e >> 7, o = e & 127;
    float mx = 0.f;
    for (int k = 0; k < 20; k++) mx = fmaxf(mx, bf2f(s_v[pt * 20 + k][o]));
    featb[(size_t)(p0 + pt) * 512 + o] = f2bf(mx);
  }
  // ---- dg2: A=s_v(80x128), W=w2b, relu -> s_a (reuse) ----
  {
    floatx4 acc[5][2];
    #pragma unroll
    for (int mt = 0; mt < 5; mt++) { acc[mt][0] = (floatx4)0.f; acc[mt][1] = (floatx4)0.f; }
    #pragma unroll
    for (int ks = 0; ks < 4; ks++) {
      int k0 = ks * 32 + quad * 8;
      short8 w0 = *(const short8*)(w2b + (nblock + mrow) * 128 + k0);
      short8 w1v = *(const short8*)(w2b + (nblock + 16 + mrow) * 128 + k0);
      #pragma unroll
      for (int mt = 0; mt < 5; mt++) {
        short8 a = *(short8*)&s_v[mt * 16 + mrow][k0];
        acc[mt][0] = mfma_bf16(a, w0, acc[mt][0]);
        acc[mt][1] = mfma_bf16(a, w1v, acc[mt][1]);
      }
    }
    #pragma unroll
    for (int ns = 0; ns < 2; ns++) {
      int o = nblock + ns * 16 + mrow;
      float bz = bia2[o];
      #pragma unroll
      for (int mt = 0; mt < 5; mt++)
        #pragma unroll
        for (int r = 0; r < 4; r++)
          s_a[mt * 16 + quad * 4 + r][o] = f2bf(fmaxf(acc[mt][ns][r] + bz, 0.f));
    }
  }
  __syncthreads();
  // ---- x2 = max_k dg2 ----
  #pragma unroll
  for (int it = 0; it < 2; it++) {
    int e = t + it * 256;
    int pt = e >> 7, o = e & 127;
    float mx = 0.f;
    for (int k = 0; k < 20; k++) mx = fmaxf(mx, bf2f(s_a[pt * 20 + k][o]));
    featb[(size_t)(p0 + pt) * 512 + 128 + o] = f2bf(mx);
  }
}

// ---------------- K4: sn stage, 4 points/block, M=80 -------------------------
// A = [x2_nbr | x2_ctr] (pure copies; subtraction folded into wsn1b').
__global__ __launch_bounds__(256) void sn_stage(
    const int* __restrict__ idx2, const unsigned short* __restrict__ wb,
    const float* __restrict__ bias, unsigned short* __restrict__ featb) {
  __shared__ unsigned short s_a[80][264];   // row stride 528 B (16B-aligned)
  __shared__ int s_nbf[80];
  int p0 = blockIdx.x * 4;
  int b = p0 >> 12, n0 = p0 & 4095;
  int bb = b << 12;
  int t = threadIdx.x;
  int lane = t & 63, wave = t >> 6;
  if (t < 80) s_nbf[t] = idx2[p0 * 20 + t];
  __syncthreads();
  {
    int cc = (t & 31) * 8;                  // uniform per-thread
    int r00 = t >> 5;
    #pragma unroll
    for (int it = 0; it < 10; it++) {
      int row = r00 + it * 8;
      const unsigned short* src = (cc < 128)
        ? featb + (size_t)(bb + s_nbf[row]) * 512 + 128 + cc
        : featb + (size_t)(bb + n0 + row / 20) * 512 + cc;   // 128+(cc-128)
      *(short8*)&s_a[row][cc] = *(const short8*)src;
    }
  }
  __syncthreads();
  int quad = lane >> 4, mrow = lane & 15;
  int nblock = wave * 64;
  floatx4 acc[5][4];
  #pragma unroll
  for (int mt = 0; mt < 5; mt++)
    #pragma unroll
    for (int ns = 0; ns < 4; ns++) acc[mt][ns] = (floatx4)0.f;
  #pragma unroll
  for (int ks = 0; ks < 8; ks++) {
    int k0 = ks * 32 + quad * 8;
    short8 w[4];
    #pragma unroll
    for (int ns = 0; ns < 4; ns++)
      w[ns] = *(const short8*)(wb + (nblock + ns * 16 + mrow) * 256 + k0);
    #pragma unroll
    for (int mt = 0; mt < 5; mt++) {
      short8 a = *(short8*)&s_a[mt * 16 + mrow][k0];
      #pragma unroll
      for (int ns = 0; ns < 4; ns++)
        acc[mt][ns] = mfma_bf16(a, w[ns], acc[mt][ns]);
    }
  }
  __syncthreads();                          // all s_a reads done
  #pragma unroll
  for (int ns = 0; ns < 4; ns++) {
    int o = nblock + ns * 16 + mrow;
    float bz = bias[o];
    #pragma unroll
    for (int mt = 0; mt < 5; mt++)
      #pragma unroll
      for (int r = 0; r < 4; r++)
        s_a[mt * 16 + quad * 4 + r][o] = f2bf(fmaxf(acc[mt][ns][r] + bz, 0.f));
  }
  __syncthreads();
  #pragma unroll
  for (int it = 0; it < 4; it++) {
    int e = t + it * 256;                   // 1024 outputs
    int pt = e >> 8, o = e & 255;
    float mx = 0.f;
    for (int k = 0; k < 20; k++) mx = fmaxf(mx, bf2f(s_a[pt * 20 + k][o]));
    featb[(size_t)(p0 + pt) * 512 + 256 + o] = f2bf(mx);
  }
}

// ---------------- K5: conv3 GEMM ---------------------------------------------
__global__ __launch_bounds__(256) void conv3_gemm(
    const unsigned short* __restrict__ w3b, const unsigned short* __restrict__ featb,
    const float* __restrict__ b3, float* __restrict__ out) {
  __shared__ unsigned short s_a[128][40];
  __shared__ unsigned short s_b[128][40];
  int o0 = blockIdx.x * 128, p0 = blockIdx.y * 128;
  int t = threadIdx.x, lane = t & 63, wave = t >> 6;
  int wy = wave >> 1, wx = wave & 1;
  int quad = lane >> 4, l15 = lane & 15;
  floatx4 acc[4][4];
  #pragma unroll
  for (int i = 0; i < 4; i++)
    #pragma unroll
    for (int j = 0; j < 4; j++) acc[i][j] = (floatx4)0.f;
  for (int kc = 0; kc < 16; kc++) {
    __syncthreads();
    for (int e = t; e < 512; e += 256) {
      int r = e >> 2, c8 = (e & 3) * 8;
      *(short8*)&s_a[r][c8] = *(const short8*)(w3b + (size_t)(o0 + r) * 512 + kc * 32 + c8);
    }
    for (int e = t; e < 512; e += 256) {
      int r = e >> 2, c8 = (e & 3) * 8;
      *(short8*)&s_b[r][c8] = *(const short8*)(featb + (size_t)(p0 + r) * 512 + kc * 32 + c8);
    }
    __syncthreads();
    int k0 = quad * 8;
    short8 af[4], bfr[4];
    #pragma unroll
    for (int i = 0; i < 4; i++) af[i] = *(short8*)&s_a[wy * 64 + i * 16 + l15][k0];
    #pragma unroll
    for (int j = 0; j < 4; j++) bfr[j] = *(short8*)&s_b[wx * 64 + j * 16 + l15][k0];
    #pragma unroll
    for (int i = 0; i < 4; i++)
      #pragma unroll
      for (int j = 0; j < 4; j++) acc[i][j] = mfma_bf16(af[i], bfr[j], acc[i][j]);
  }
  #pragma unroll
  for (int i = 0; i < 4; i++)
    #pragma unroll
    for (int j = 0; j < 4; j++) {
      int pl = p0 + wx * 64 + j * 16 + l15;
      int bI = pl >> 12, n = pl & 4095;
      #pragma unroll
      for (int r = 0; r < 4; r++) {
        int o = o0 + wy * 64 + i * 16 + quad * 4 + r;
        out[(size_t)(bI * 1024 + o) * 4096 + n] = fmaxf(acc[i][j][r] + b3[o], 0.f);
      }
    }
}

// ---------------- launcher ---------------------------------------------------
extern "C" void kernel_launch(void* const* d_in, const int* in_sizes, int n_in,
                              void* d_out, int out_size, void* d_ws, size_t ws_size,
                              hipStream_t stream) {
  const float* x    = (const float*)d_in[0];
  const float* w1   = (const float*)d_in[1];
  const float* b1   = (const float*)d_in[2];
  const float* w2   = (const float*)d_in[3];
  const float* b2   = (const float*)d_in[4];
  const float* wdg1 = (const float*)d_in[5];
  const float* bdg1 = (const float*)d_in[6];
  const float* wdg2 = (const float*)d_in[7];
  const float* bdg2 = (const float*)d_in[8];
  const float* wsn1 = (const float*)d_in[9];
  const float* bsn1 = (const float*)d_in[10];
  const float* w3   = (const float*)d_in[11];
  const float* b3   = (const float*)d_in[12];

  float* ws = (float*)d_ws;                 // offsets in float slots
  float* h  = ws;                           // 2,097,152
  float* hh = ws + 2097152;                 //    32,768
  float* cc = ws + 2129920;                 //    32,768
  int* idx1 = (int*)(ws + 2162688);         //   655,360
  int* idx2 = (int*)(ws + 2818048);         //   655,360
  unsigned short* featb = (unsigned short*)(ws + 3473408);   // 16,777,216 bf16
  unsigned short* wdg1b = (unsigned short*)(ws + 11862016);
  unsigned short* wdg2b = (unsigned short*)(ws + 11870208);
  unsigned short* wsn1b = (unsigned short*)(ws + 11878400);
  unsigned short* w3b   = (unsigned short*)(ws + 11911168);
  unsigned short* hb16  = (unsigned short*)(ws + 12173312); // 2,097,152 bf16

  cvt_weights<<<2048, 256, 0, stream>>>(wdg1, wdg1b, wdg2, wdg2b,
                                        wsn1, wsn1b, w3, w3b);
  conv12<<<8192, 256, 0, stream>>>(x, w1, b1, w2, b2, h, hb16, hh, cc);
  knn_topk<64><<<dim3(64, 8), 256, 0, stream>>>(h, hh, idx1);
  knn_topk<3><<<dim3(64, 8), 256, 0, stream>>>(x, cc, idx2);
  dg_stage<<<8192, 256, 0, stream>>>(hb16, idx1, wdg1b, bdg1, wdg2b, bdg2, featb);
  sn_stage<<<8192, 256, 0, stream>>>(idx2, wsn1b, bsn1, featb);
  conv3_gemm<<<dim3(8, 256), 256, 0, stream>>>(w3b, featb, b3, (float*)d_out);
}

// Round 7
// 1073.794 us; speedup vs baseline: 12.9473x; 1.1558x over previous
//
#include <hip/hip_runtime.h>
#include <stdint.h>

// LPDNet forward on gfx950.
// Layout decisions:
//   hb16/hlo16 : (B,N,64) bf16 hi/lo split of h -> MFMA knn + pure-copy gather
//   featb : (B,N,512) bf16 rows -> [x1 | x2 | x3]; feeds conv3 GEMM and x2 gather
//   idx1/idx2 : (B,N,20) int32
// Graph-conv trick: W·[nbr-ctr | ctr] == W'·[nbr | ctr] with W' = [Wn | Wc-Wn]
// (transformed once in cvt_weights) -> gather staging is pure short8 copies.
// knn64: inner products via 4-term split-bf16 MFMA (hi/lo), residual ~1e-8 --
// comparable to fp32-chain rounding (which has produced 0 neighbor flips).
// bf16 conv path (fp32 accum); tolerance is 2% of max|ref|.

#define NB 8
#define NP 4096
#define NPTS (NB*NP)

typedef float  floatx4 __attribute__((ext_vector_type(4)));
typedef short  short8  __attribute__((ext_vector_type(8)));

__device__ __forceinline__ unsigned short f2bf(float f) {
  union { float f; uint32_t u; } v; v.f = f;
  uint32_t r = v.u + 0x7fffu + ((v.u >> 16) & 1u);   // RNE
  return (unsigned short)(r >> 16);
}
__device__ __forceinline__ float bf2f(unsigned short h) {
  union { uint32_t u; float f; } v; v.u = ((uint32_t)h) << 16;
  return v.f;
}

__device__ __forceinline__ floatx4 mfma_bf16(short8 a, short8 b, floatx4 c) {
  return __builtin_amdgcn_mfma_f32_16x16x32_bf16(a, b, c, 0, 0, 0);
}

// ---------------- K0: weight conversion + graph-fold transform ---------------
__global__ void cvt_weights(const float* wdg1, unsigned short* wdg1b,
                            const float* wdg2, unsigned short* wdg2b,
                            const float* wsn1, unsigned short* wsn1b,
                            const float* w3, unsigned short* w3b) {
  int i = blockIdx.x * 256 + threadIdx.x;
  if (i < 16384) {                       // wdg1' = [Wn | Wc-Wn], C=64
    int c = i & 127;
    wdg1b[i] = f2bf(wdg1[i] - (c >= 64 ? wdg1[i - 64] : 0.f));
  }
  if (i < 16384) wdg2b[i] = f2bf(wdg2[i]);
  if (i < 65536) {                       // wsn1' = [Wn | Wc-Wn], C=128
    int c = i & 255;
    wsn1b[i] = f2bf(wsn1[i] - (c >= 128 ? wsn1[i - 128] : 0.f));
  }
  if (i < 524288) w3b[i] = f2bf(w3[i]);
}

// ---------------- K1: conv1+relu, conv2+relu -> h hi/lo bf16, xx sums --------
__global__ __launch_bounds__(256) void conv12(
    const float* __restrict__ xin, const float* __restrict__ w1,
    const float* __restrict__ b1, const float* __restrict__ w2,
    const float* __restrict__ b2,
    unsigned short* __restrict__ hb16, unsigned short* __restrict__ hlo16,
    float* __restrict__ hh, float* __restrict__ cc) {
  int wave = threadIdx.x >> 6, lane = threadIdx.x & 63;
  int p = blockIdx.x * 4 + wave;                    // grid 8192
  __shared__ float s_h1[4][64];
  const float* xp = xin + p * 3;
  float c0 = xp[0], c1 = xp[1], c2 = xp[2];
  float v = b1[lane] + w1[lane*3+0]*c0 + w1[lane*3+1]*c1 + w1[lane*3+2]*c2;
  s_h1[wave][lane] = fmaxf(v, 0.f);
  __syncthreads();
  float acc = b2[lane];
  const float* wr = w2 + lane * 64;
  #pragma unroll
  for (int c = 0; c < 64; c += 4) {
    floatx4 w4 = *(const floatx4*)(wr + c);
    acc += w4[0]*s_h1[wave][c]   + w4[1]*s_h1[wave][c+1]
         + w4[2]*s_h1[wave][c+2] + w4[3]*s_h1[wave][c+3];
  }
  acc = fmaxf(acc, 0.f);
  unsigned short hi = f2bf(acc);
  hb16[p*64 + lane] = hi;
  hlo16[p*64 + lane] = f2bf(acc - bf2f(hi));
  float sq = acc * acc;
  #pragma unroll
  for (int off = 32; off; off >>= 1) sq += __shfl_xor(sq, off, 64);
  if (lane == 0) { hh[p] = sq; cc[p] = c0*c0 + c1*c1 + c2*c2; }
}

// ---------------- K2a: knn C=64 via split-bf16 MFMA + ballot top-20 ----------
// 64 rows/block. Wave w owns rows 16w..16w+15: A-frags (hi/lo, 2 k-steps)
// loaded once from global. Per m-tile: stage mhi/mlo (bf16) + xxM; 4 n-tiles x
// 2 k-steps x 4 chained MFMAs -> inner; score = 2*acc - xxR - xxM written to
// dots in C/D layout (row=quad*4+reg, col=lane&15 -- proven in dg/sn/conv3).
// Selection = R5 ballot machinery, unchanged (wave selects its own dots rows).
__global__ __launch_bounds__(256) void knn64_mfma(
    const unsigned short* __restrict__ Hhi, const unsigned short* __restrict__ Hlo,
    const float* __restrict__ XX, int* __restrict__ idx_out) {
  __shared__ unsigned short mhi[64][72];   // stride 72: 16B-aligned rows
  __shared__ unsigned short mlo[64][72];
  __shared__ float dots[64][68];
  __shared__ float xxR[64];
  __shared__ float xxM[64];
  __shared__ float tau[64];
  int b = blockIdx.y;
  int r0 = blockIdx.x * 64;
  int t = threadIdx.x;
  int lane = t & 63, wave = t >> 6;
  int quad = lane >> 4, l15 = lane & 15;
  const unsigned short* Hhib = Hhi + (size_t)b * NP * 64;
  const unsigned short* Hlob = Hlo + (size_t)b * NP * 64;
  short8 ahi[2], alo[2];
  {
    const unsigned short* pr = Hhib + (size_t)(r0 + wave * 16 + l15) * 64 + quad * 8;
    const unsigned short* pl = Hlob + (size_t)(r0 + wave * 16 + l15) * 64 + quad * 8;
    ahi[0] = *(const short8*)pr; ahi[1] = *(const short8*)(pr + 32);
    alo[0] = *(const short8*)pl; alo[1] = *(const short8*)(pl + 32);
  }
  if (t < 64) { xxR[t] = XX[b * NP + r0 + t]; tau[t] = -__builtin_inff(); }

  float lv[20]; int li[20];
  #pragma unroll
  for (int s = 0; s < 20; s++) { lv[s] = -__builtin_inff(); li[s] = 0x7fffffff; }
  float minval = -__builtin_inff(); int minpos = 0;
  int row = t >> 2, sub = t & 3;

  for (int mt = 0; mt < NP / 64; mt++) {
    int m0 = mt * 64;
    {                                      // stage m-tile hi/lo (pure copies)
      int pt = t >> 2, c0 = (t & 3) * 16;
      const unsigned short* sh = Hhib + (size_t)(m0 + pt) * 64 + c0;
      const unsigned short* sl = Hlob + (size_t)(m0 + pt) * 64 + c0;
      *(short8*)&mhi[pt][c0]     = *(const short8*)sh;
      *(short8*)&mhi[pt][c0 + 8] = *(const short8*)(sh + 8);
      *(short8*)&mlo[pt][c0]     = *(const short8*)sl;
      *(short8*)&mlo[pt][c0 + 8] = *(const short8*)(sl + 8);
    }
    if (t < 64) xxM[t] = XX[b * NP + m0 + t];
    __syncthreads();                       // staging visible; prev select done
    #pragma unroll
    for (int nt = 0; nt < 4; nt++) {
      floatx4 acc = (floatx4)0.f;
      #pragma unroll
      for (int ks = 0; ks < 2; ks++) {
        int k0 = ks * 32 + quad * 8;
        short8 bhi = *(short8*)&mhi[nt * 16 + l15][k0];
        short8 blo = *(short8*)&mlo[nt * 16 + l15][k0];
        acc = mfma_bf16(ahi[ks], bhi, acc);
        acc = mfma_bf16(ahi[ks], blo, acc);
        acc = mfma_bf16(alo[ks], bhi, acc);
        acc = mfma_bf16(alo[ks], blo, acc);
      }
      int colg = nt * 16 + l15;
      float xm = xxM[colg];
      #pragma unroll
      for (int r = 0; r < 4; r++) {
        int mr = wave * 16 + quad * 4 + r;
        dots[mr][colg] = 2.f * acc[r] - xxR[mr] - xm;
      }
    }
    __syncthreads();                       // dots ready
    // ---- R5 ballot selection ----
    float gate = fmaxf(minval, tau[row]);
    floatx4 dv0 = *(floatx4*)&dots[row][sub * 16];
    floatx4 dv1 = *(floatx4*)&dots[row][sub * 16 + 4];
    floatx4 dv2 = *(floatx4*)&dots[row][sub * 16 + 8];
    floatx4 dv3 = *(floatx4*)&dots[row][sub * 16 + 12];
    uint32_t mask = 0;
    #pragma unroll
    for (int j = 0; j < 4; j++) {
      if (dv0[j] > gate) mask |= 1u << j;
      if (dv1[j] > gate) mask |= 1u << (4 + j);
      if (dv2[j] > gate) mask |= 1u << (8 + j);
      if (dv3[j] > gate) mask |= 1u << (12 + j);
    }
    #pragma clang loop unroll(disable)
    for (int round = 0; round < 16; round++) {
      if (!__any(mask != 0)) break;
      if (mask) {
        int i = __builtin_ctz(mask); mask &= mask - 1;
        float v = dots[row][sub * 16 + i];
        if (v > minval) {
          int gi = m0 + sub * 16 + i;
          #pragma unroll
          for (int s = 0; s < 20; s++)
            if (s == minpos) { lv[s] = v; li[s] = gi; }
          minval = __builtin_inff();
          #pragma unroll
          for (int s = 0; s < 20; s++)
            if (lv[s] < minval) { minval = lv[s]; minpos = s; }
        }
      }
    }
    tau[row] = fmaxf(tau[row], minval);
  }
  int base = (b * NP + r0 + row) * 20;
  for (int sel = 0; sel < 20; sel++) {
    float mybv = -__builtin_inff(); int mybi = 0x7fffffff, mybs = 0;
    #pragma unroll
    for (int s = 0; s < 20; s++) {
      bool better = lv[s] > mybv || (lv[s] == mybv && li[s] < mybi);
      if (better) { mybv = lv[s]; mybi = li[s]; mybs = s; }
    }
    float bv = mybv; int bi = mybi;
    float ov = __shfl_xor(bv, 1, 64); int oi = __shfl_xor(bi, 1, 64);
    if (ov > bv || (ov == bv && oi < bi)) { bv = ov; bi = oi; }
    ov = __shfl_xor(bv, 2, 64); oi = __shfl_xor(bi, 2, 64);
    if (ov > bv || (ov == bv && oi < bi)) { bv = ov; bi = oi; }
    if (sub == 0) idx_out[base + sel] = bi;
    if (bi == mybi) {
      #pragma unroll
      for (int s = 0; s < 20; s++)
        if (s == mybs) { lv[s] = -__builtin_inff(); li[s] = 0x7fffffff; }
    }
  }
}

// ---------------- K2b: knn C=3 (fp32 vector path, R5-proven) -----------------
template<int C>
__global__ __launch_bounds__(256) void knn_topk(
    const float* __restrict__ X, const float* __restrict__ XX,
    int* __restrict__ idx_out) {
  __shared__ float rowsT[C][68];
  __shared__ float mT[C][68];
  __shared__ float dots[64][68];
  __shared__ float xxR[64];
  __shared__ float xxM[64];
  __shared__ float tau[64];
  int b = blockIdx.y;
  int r0 = blockIdx.x * 64;
  int t = threadIdx.x;
  const float* Xb = X + (size_t)b * NP * C;
  for (int e = t; e < C * 64; e += 256) {
    int r = e / C, c = e - r * C;
    rowsT[c][r] = Xb[(r0 + r) * C + c];
  }
  if (t < 64) { xxR[t] = XX[b * NP + r0 + t]; tau[t] = -__builtin_inff(); }

  float lv[20]; int li[20];
  #pragma unroll
  for (int s = 0; s < 20; s++) { lv[s] = -__builtin_inff(); li[s] = 0x7fffffff; }
  float minval = -__builtin_inff(); int minpos = 0;

  int tm = t & 15, tr = t >> 4;
  int row = t >> 2, sub = t & 3;

  for (int mt = 0; mt < NP / 64; mt++) {
    int m0 = mt * 64;
    for (int e = t; e < C * 64; e += 256) {
      int r = e / C, c = e - r * C;
      mT[c][r] = Xb[(m0 + r) * C + c];
    }
    if (t < 64) xxM[t] = XX[b * NP + m0 + t];
    __syncthreads();
    float acc[4][4];
    #pragma unroll
    for (int i = 0; i < 4; i++)
      #pragma unroll
      for (int j = 0; j < 4; j++) acc[i][j] = 0.f;
    for (int c = 0; c < C; c++) {
      floatx4 av = *(floatx4*)&rowsT[c][tr * 4];
      floatx4 bv = *(floatx4*)&mT[c][tm * 4];
      #pragma unroll
      for (int i = 0; i < 4; i++)
        #pragma unroll
        for (int j = 0; j < 4; j++) acc[i][j] += av[i] * bv[j];
    }
    #pragma unroll
    for (int i = 0; i < 4; i++) {
      floatx4 sv;
      #pragma unroll
      for (int j = 0; j < 4; j++)
        sv[j] = 2.f * acc[i][j] - xxR[tr*4 + i] - xxM[tm*4 + j];
      *(floatx4*)&dots[tr*4 + i][tm*4] = sv;
    }
    __syncthreads();
    float gate = fmaxf(minval, tau[row]);
    floatx4 dv0 = *(floatx4*)&dots[row][sub * 16];
    floatx4 dv1 = *(floatx4*)&dots[row][sub * 16 + 4];
    floatx4 dv2 = *(floatx4*)&dots[row][sub * 16 + 8];
    floatx4 dv3 = *(floatx4*)&dots[row][sub * 16 + 12];
    uint32_t mask = 0;
    #pragma unroll
    for (int j = 0; j < 4; j++) {
      if (dv0[j] > gate) mask |= 1u << j;
      if (dv1[j] > gate) mask |= 1u << (4 + j);
      if (dv2[j] > gate) mask |= 1u << (8 + j);
      if (dv3[j] > gate) mask |= 1u << (12 + j);
    }
    #pragma clang loop unroll(disable)
    for (int round = 0; round < 16; round++) {
      if (!__any(mask != 0)) break;
      if (mask) {
        int i = __builtin_ctz(mask); mask &= mask - 1;
        float v = dots[row][sub * 16 + i];
        if (v > minval) {
          int gi = m0 + sub * 16 + i;
          #pragma unroll
          for (int s = 0; s < 20; s++)
            if (s == minpos) { lv[s] = v; li[s] = gi; }
          minval = __builtin_inff();
          #pragma unroll
          for (int s = 0; s < 20; s++)
            if (lv[s] < minval) { minval = lv[s]; minpos = s; }
        }
      }
    }
    tau[row] = fmaxf(tau[row], minval);
  }
  int base = (b * NP + r0 + row) * 20;
  for (int sel = 0; sel < 20; sel++) {
    float mybv = -__builtin_inff(); int mybi = 0x7fffffff, mybs = 0;
    #pragma unroll
    for (int s = 0; s < 20; s++) {
      bool better = lv[s] > mybv || (lv[s] == mybv && li[s] < mybi);
      if (better) { mybv = lv[s]; mybi = li[s]; mybs = s; }
    }
    float bv = mybv; int bi = mybi;
    float ov = __shfl_xor(bv, 1, 64); int oi = __shfl_xor(bi, 1, 64);
    if (ov > bv || (ov == bv && oi < bi)) { bv = ov; bi = oi; }
    ov = __shfl_xor(bv, 2, 64); oi = __shfl_xor(bi, 2, 64);
    if (ov > bv || (ov == bv && oi < bi)) { bv = ov; bi = oi; }
    if (sub == 0) idx_out[base + sel] = bi;
    if (bi == mybi) {
      #pragma unroll
      for (int s = 0; s < 20; s++)
        if (s == mybs) { lv[s] = -__builtin_inff(); li[s] = 0x7fffffff; }
    }
  }
}

// ---------------- K3: dg stage, 4 points/block, M=80 (zero padding) ----------
__global__ __launch_bounds__(256) void dg_stage(
    const unsigned short* __restrict__ hb16, const int* __restrict__ idx1,
    const unsigned short* __restrict__ w1b, const float* __restrict__ bia1,
    const unsigned short* __restrict__ w2b, const float* __restrict__ bia2,
    unsigned short* __restrict__ featb) {
  __shared__ unsigned short s_a[80][136];   // row stride 272 B (16B-aligned)
  __shared__ unsigned short s_v[80][136];
  __shared__ int s_nbf[80];
  int p0 = blockIdx.x * 4;                  // grid 8192; 4 pts share batch b
  int b = p0 >> 12, n0 = p0 & 4095;
  int t = threadIdx.x;
  int lane = t & 63, wave = t >> 6;
  if (t < 80) s_nbf[t] = idx1[p0 * 20 + t];
  __syncthreads();
  const unsigned short* hbb = hb16 + (size_t)b * NP * 64;
  {
    int cc = (t & 15) * 8;                  // uniform per-thread across iters
    int r00 = t >> 4;
    #pragma unroll
    for (int it = 0; it < 5; it++) {
      int row = r00 + it * 16;
      const unsigned short* src = (cc < 64)
        ? hbb + (size_t)s_nbf[row] * 64 + cc
        : hbb + (size_t)(n0 + row / 20) * 64 + (cc - 64);
      *(short8*)&s_a[row][cc] = *(const short8*)src;
    }
  }
  __syncthreads();
  int quad = lane >> 4, mrow = lane & 15;
  int nblock = wave * 32;
  // ---- dg1: A=s_a(80x128), W=w1b' ----
  {
    floatx4 acc[5][2];
    #pragma unroll
    for (int mt = 0; mt < 5; mt++) { acc[mt][0] = (floatx4)0.f; acc[mt][1] = (floatx4)0.f; }
    #pragma unroll
    for (int ks = 0; ks < 4; ks++) {
      int k0 = ks * 32 + quad * 8;
      short8 w0 = *(const short8*)(w1b + (nblock + mrow) * 128 + k0);
      short8 w1v = *(const short8*)(w1b + (nblock + 16 + mrow) * 128 + k0);
      #pragma unroll
      for (int mt = 0; mt < 5; mt++) {
        short8 a = *(short8*)&s_a[mt * 16 + mrow][k0];
        acc[mt][0] = mfma_bf16(a, w0, acc[mt][0]);
        acc[mt][1] = mfma_bf16(a, w1v, acc[mt][1]);
      }
    }
    #pragma unroll
    for (int ns = 0; ns < 2; ns++) {
      int o = nblock + ns * 16 + mrow;
      float bz = bia1[o];
      #pragma unroll
      for (int mt = 0; mt < 5; mt++)
        #pragma unroll
        for (int r = 0; r < 4; r++)
          s_v[mt * 16 + quad * 4 + r][o] = f2bf(fmaxf(acc[mt][ns][r] + bz, 0.f));
    }
  }
  __syncthreads();                          // s_v ready; all s_a reads done
  #pragma unroll
  for (int it = 0; it < 2; it++) {
    int e = t + it * 256;                   // 512 outputs
    int pt = e >> 7, o = e & 127;
    float mx = 0.f;
    for (int k = 0; k < 20; k++) mx = fmaxf(mx, bf2f(s_v[pt * 20 + k][o]));
    featb[(size_t)(p0 + pt) * 512 + o] = f2bf(mx);
  }
  // ---- dg2: A=s_v(80x128), W=w2b, relu -> s_a (reuse) ----
  {
    floatx4 acc[5][2];
    #pragma unroll
    for (int mt = 0; mt < 5; mt++) { acc[mt][0] = (floatx4)0.f; acc[mt][1] = (floatx4)0.f; }
    #pragma unroll
    for (int ks = 0; ks < 4; ks++) {
      int k0 = ks * 32 + quad * 8;
      short8 w0 = *(const short8*)(w2b + (nblock + mrow) * 128 + k0);
      short8 w1v = *(const short8*)(w2b + (nblock + 16 + mrow) * 128 + k0);
      #pragma unroll
      for (int mt = 0; mt < 5; mt++) {
        short8 a = *(short8*)&s_v[mt * 16 + mrow][k0];
        acc[mt][0] = mfma_bf16(a, w0, acc[mt][0]);
        acc[mt][1] = mfma_bf16(a, w1v, acc[mt][1]);
      }
    }
    #pragma unroll
    for (int ns = 0; ns < 2; ns++) {
      int o = nblock + ns * 16 + mrow;
      float bz = bia2[o];
      #pragma unroll
      for (int mt = 0; mt < 5; mt++)
        #pragma unroll
        for (int r = 0; r < 4; r++)
          s_a[mt * 16 + quad * 4 + r][o] = f2bf(fmaxf(acc[mt][ns][r] + bz, 0.f));
    }
  }
  __syncthreads();
  #pragma unroll
  for (int it = 0; it < 2; it++) {
    int e = t + it * 256;
    int pt = e >> 7, o = e & 127;
    float mx = 0.f;
    for (int k = 0; k < 20; k++) mx = fmaxf(mx, bf2f(s_a[pt * 20 + k][o]));
    featb[(size_t)(p0 + pt) * 512 + 128 + o] = f2bf(mx);
  }
}

// ---------------- K4: sn stage, 4 points/block, M=80 -------------------------
__global__ __launch_bounds__(256) void sn_stage(
    const int* __restrict__ idx2, const unsigned short* __restrict__ wb,
    const float* __restrict__ bias, unsigned short* __restrict__ featb) {
  __shared__ unsigned short s_a[80][264];   // row stride 528 B (16B-aligned)
  __shared__ int s_nbf[80];
  int p0 = blockIdx.x * 4;
  int b = p0 >> 12, n0 = p0 & 4095;
  int bb = b << 12;
  int t = threadIdx.x;
  int lane = t & 63, wave = t >> 6;
  if (t < 80) s_nbf[t] = idx2[p0 * 20 + t];
  __syncthreads();
  {
    int cc = (t & 31) * 8;                  // uniform per-thread
    int r00 = t >> 5;
    #pragma unroll
    for (int it = 0; it < 10; it++) {
      int row = r00 + it * 8;
      const unsigned short* src = (cc < 128)
        ? featb + (size_t)(bb + s_nbf[row]) * 512 + 128 + cc
        : featb + (size_t)(bb + n0 + row / 20) * 512 + cc;   // 128+(cc-128)
      *(short8*)&s_a[row][cc] = *(const short8*)src;
    }
  }
  __syncthreads();
  int quad = lane >> 4, mrow = lane & 15;
  int nblock = wave * 64;
  floatx4 acc[5][4];
  #pragma unroll
  for (int mt = 0; mt < 5; mt++)
    #pragma unroll
    for (int ns = 0; ns < 4; ns++) acc[mt][ns] = (floatx4)0.f;
  #pragma unroll
  for (int ks = 0; ks < 8; ks++) {
    int k0 = ks * 32 + quad * 8;
    short8 w[4];
    #pragma unroll
    for (int ns = 0; ns < 4; ns++)
      w[ns] = *(const short8*)(wb + (nblock + ns * 16 + mrow) * 256 + k0);
    #pragma unroll
    for (int mt = 0; mt < 5; mt++) {
      short8 a = *(short8*)&s_a[mt * 16 + mrow][k0];
      #pragma unroll
      for (int ns = 0; ns < 4; ns++)
        acc[mt][ns] = mfma_bf16(a, w[ns], acc[mt][ns]);
    }
  }
  __syncthreads();                          // all s_a reads done
  #pragma unroll
  for (int ns = 0; ns < 4; ns++) {
    int o = nblock + ns * 16 + mrow;
    float bz = bias[o];
    #pragma unroll
    for (int mt = 0; mt < 5; mt++)
      #pragma unroll
      for (int r = 0; r < 4; r++)
        s_a[mt * 16 + quad * 4 + r][o] = f2bf(fmaxf(acc[mt][ns][r] + bz, 0.f));
  }
  __syncthreads();
  #pragma unroll
  for (int it = 0; it < 4; it++) {
    int e = t + it * 256;                   // 1024 outputs
    int pt = e >> 8, o = e & 255;
    float mx = 0.f;
    for (int k = 0; k < 20; k++) mx = fmaxf(mx, bf2f(s_a[pt * 20 + k][o]));
    featb[(size_t)(p0 + pt) * 512 + 256 + o] = f2bf(mx);
  }
}

// ---------------- K5: conv3 GEMM ---------------------------------------------
__global__ __launch_bounds__(256) void conv3_gemm(
    const unsigned short* __restrict__ w3b, const unsigned short* __restrict__ featb,
    const float* __restrict__ b3, float* __restrict__ out) {
  __shared__ unsigned short s_a[128][40];
  __shared__ unsigned short s_b[128][40];
  int o0 = blockIdx.x * 128, p0 = blockIdx.y * 128;
  int t = threadIdx.x, lane = t & 63, wave = t >> 6;
  int wy = wave >> 1, wx = wave & 1;
  int quad = lane >> 4, l15 = lane & 15;
  floatx4 acc[4][4];
  #pragma unroll
  for (int i = 0; i < 4; i++)
    #pragma unroll
    for (int j = 0; j < 4; j++) acc[i][j] = (floatx4)0.f;
  for (int kc = 0; kc < 16; kc++) {
    __syncthreads();
    for (int e = t; e < 512; e += 256) {
      int r = e >> 2, c8 = (e & 3) * 8;
      *(short8*)&s_a[r][c8] = *(const short8*)(w3b + (size_t)(o0 + r) * 512 + kc * 32 + c8);
    }
    for (int e = t; e < 512; e += 256) {
      int r = e >> 2, c8 = (e & 3) * 8;
      *(short8*)&s_b[r][c8] = *(const short8*)(featb + (size_t)(p0 + r) * 512 + kc * 32 + c8);
    }
    __syncthreads();
    int k0 = quad * 8;
    short8 af[4], bfr[4];
    #pragma unroll
    for (int i = 0; i < 4; i++) af[i] = *(short8*)&s_a[wy * 64 + i * 16 + l15][k0];
    #pragma unroll
    for (int j = 0; j < 4; j++) bfr[j] = *(short8*)&s_b[wx * 64 + j * 16 + l15][k0];
    #pragma unroll
    for (int i = 0; i < 4; i++)
      #pragma unroll
      for (int j = 0; j < 4; j++) acc[i][j] = mfma_bf16(af[i], bfr[j], acc[i][j]);
  }
  #pragma unroll
  for (int i = 0; i < 4; i++)
    #pragma unroll
    for (int j = 0; j < 4; j++) {
      int pl = p0 + wx * 64 + j * 16 + l15;
      int bI = pl >> 12, n = pl & 4095;
      #pragma unroll
      for (int r = 0; r < 4; r++) {
        int o = o0 + wy * 64 + i * 16 + quad * 4 + r;
        out[(size_t)(bI * 1024 + o) * 4096 + n] = fmaxf(acc[i][j][r] + b3[o], 0.f);
      }
    }
}

// ---------------- launcher ---------------------------------------------------
extern "C" void kernel_launch(void* const* d_in, const int* in_sizes, int n_in,
                              void* d_out, int out_size, void* d_ws, size_t ws_size,
                              hipStream_t stream) {
  const float* x    = (const float*)d_in[0];
  const float* w1   = (const float*)d_in[1];
  const float* b1   = (const float*)d_in[2];
  const float* w2   = (const float*)d_in[3];
  const float* b2   = (const float*)d_in[4];
  const float* wdg1 = (const float*)d_in[5];
  const float* bdg1 = (const float*)d_in[6];
  const float* wdg2 = (const float*)d_in[7];
  const float* bdg2 = (const float*)d_in[8];
  const float* wsn1 = (const float*)d_in[9];
  const float* bsn1 = (const float*)d_in[10];
  const float* w3   = (const float*)d_in[11];
  const float* b3   = (const float*)d_in[12];

  float* ws = (float*)d_ws;                 // offsets in float slots
  unsigned short* hlo16 = (unsigned short*)ws;               // 2,097,152 bf16 (1,048,576 slots)
  float* hh = ws + 2097152;                 //    32,768
  float* cc = ws + 2129920;                 //    32,768
  int* idx1 = (int*)(ws + 2162688);         //   655,360
  int* idx2 = (int*)(ws + 2818048);         //   655,360
  unsigned short* featb = (unsigned short*)(ws + 3473408);   // 16,777,216 bf16
  unsigned short* wdg1b = (unsigned short*)(ws + 11862016);
  unsigned short* wdg2b = (unsigned short*)(ws + 11870208);
  unsigned short* wsn1b = (unsigned short*)(ws + 11878400);
  unsigned short* w3b   = (unsigned short*)(ws + 11911168);
  unsigned short* hb16  = (unsigned short*)(ws + 12173312); // 2,097,152 bf16

  cvt_weights<<<2048, 256, 0, stream>>>(wdg1, wdg1b, wdg2, wdg2b,
                                        wsn1, wsn1b, w3, w3b);
  conv12<<<8192, 256, 0, stream>>>(x, w1, b1, w2, b2, hb16, hlo16, hh, cc);
  knn64_mfma<<<dim3(64, 8), 256, 0, stream>>>(hb16, hlo16, hh, idx1);
  knn_topk<3><<<dim3(64, 8), 256, 0, stream>>>(x, cc, idx2);
  dg_stage<<<8192, 256, 0, stream>>>(hb16, idx1, wdg1b, bdg1, wdg2b, bdg2, featb);
  sn_stage<<<8192, 256, 0, stream>>>(idx2, wsn1b, bsn1, featb);
  conv3_gemm<<<dim3(8, 256), 256, 0, stream>>>(w3b, featb, b3, (float*)d_out);
}